// Round 18
// baseline (186.252 us; speedup 1.0000x reference)
//
#include <hip/hip_runtime.h>

#define HWSZ 65536   // 256*256
#define CCH  64

typedef __bf16 bf16x8 __attribute__((ext_vector_type(8)));
typedef __bf16 bf16x4 __attribute__((ext_vector_type(4)));
typedef float  f32x4  __attribute__((ext_vector_type(4)));

__device__ inline void gload_lds16(const void* g, void* l) {
    __builtin_amdgcn_global_load_lds(
        (const __attribute__((address_space(1))) void*)g,
        (__attribute__((address_space(3))) void*)l, 16, 0, 0);
}

// ===========================================================================
// Prep bodies (one launch). W layouts: ci-split + 2-rows-per-128B packed +
// inverse-swizzled + DX-MAJOR slice order (slice s = dx*KSZ+dy).
// ===========================================================================

__device__ void cvt_body(int cb, const float* __restrict__ src,
                         __bf16* __restrict__ dst)
{
    int p  = cb * 256 + threadIdx.x;
    int b  = p >> 16, hw = p & 65535;
    const float* sp = src + (((size_t)b * 64) << 16) + hw;
    __bf16* dp = dst + (size_t)p * 64;
    #pragma unroll
    for (int c8 = 0; c8 < 8; ++c8) {
        bf16x8 v8;
        #pragma unroll
        for (int j = 0; j < 8; ++j)
            v8[j] = (__bf16)sp[(size_t)(c8 * 8 + j) << 16];
        *(bf16x8*)(dp + c8 * 8) = v8;
    }
}

__device__ void prep3_body(int cb, const float* __restrict__ src,
                           __bf16* __restrict__ dst)
{
    int t = cb * 256 + threadIdx.x;
    if (t >= 2 * 9 * 2048) return;
    int j  = t & 7;
    int u  = (t >> 3) & 255;
    int q  = t >> 11;
    int s  = q % 9, ci = q / 9;
    int dx = s / 3, dy = s % 3;
    int k  = dy * 3 + dx;              // dx-major slice order
    int r  = u >> 3;
    int v  = (u & 7) ^ (r & 7);
    int o  = 2 * r + (v >> 2);
    int g  = v & 3;
    int i  = ci * 32 + g * 8 + j;
    dst[t] = (__bf16)src[((size_t)o * 64 + i) * 9 + k];
}

__device__ void prep1_body(int cb, const float* __restrict__ src,
                           __bf16* __restrict__ dst)
{
    int t = cb * 256 + threadIdx.x;
    if (t >= 2 * 2048) return;
    int j  = t & 7;
    int u  = (t >> 3) & 255;
    int ci = t >> 11;
    int r  = u >> 3;
    int v  = (u & 7) ^ (r & 7);
    int o  = 2 * r + (v >> 2);
    int g  = v & 3;
    int i  = ci * 32 + g * 8 + j;
    dst[t] = (__bf16)src[(size_t)o * 64 + i];
}

__device__ void prepF_body(int cb, const float* __restrict__ mt,
                           const float* __restrict__ aw, __bf16* __restrict__ dst)
{
    int t = cb * 256 + threadIdx.x;
    if (t >= 2 * 25 * 3072) return;
    int j  = t & 7;
    int u  = (t >> 3) % 384;
    int q  = t / 3072;
    int s  = q % 25, ci = q / 25;
    int dx = s / 5, dy = s % 5;
    int k  = dy * 5 + dx;              // dx-major slice order
    int r  = u >> 3;
    int v  = (u & 7) ^ (r & 7);
    int o  = 2 * r + (v >> 2);
    int g  = v & 3;
    int i  = ci * 32 + g * 8 + j;
    float val = 0.f;
    if (o < 64)      val = mt[((size_t)o * 64 + i) * 25 + k];
    else if (o < 73) val = aw[((size_t)(o - 64) * 64 + i) * 25 + k];
    dst[t] = (__bf16)val;
}

// prep super-kernel. Grid 2528.
__global__ __launch_bounds__(256) void k_prep(
    const float* x, const float* mask,
    const float* c1w, const float* c2w,
    const float* mt1w, const float* aw1w,
    const float* mt2w, const float* aw2w,
    const float* crw,
    __bf16* xh, __bf16* mh,
    __bf16* wbc1, __bf16* wbc2, __bf16* wbF1, __bf16* wbF2, __bf16* wbcr)
{
    int bid = blockIdx.x;
    if      (bid < 512)  cvt_body(bid, x, xh);
    else if (bid < 1024) cvt_body(bid - 512, mask, mh);
    else if (bid < 1168) prep3_body(bid - 1024, c1w, wbc1);
    else if (bid < 1312) prep3_body(bid - 1168, c2w, wbc2);
    else if (bid < 1912) prepF_body(bid - 1312, mt1w, aw1w, wbF1);
    else if (bid < 2512) prepF_body(bid - 1912, mt2w, aw2w, wbF2);
    else                 prep1_body(bid - 2512, crw, wbcr);
}

// ---------------------------------------------------------------------------
// Fused 5x5 MFMA conv, 16x8 tile (grid 1024 -> 4 blocks/CU resident, 16
// waves/CU): r16 per-slice double-buffered async W staging, LDS ~28KB.
// Wave computes 80 out-ch x 2 rows (nf<2). dx-major slices: dx=s/5, dy=s%5.
// ---------------------------------------------------------------------------
template<int EPI>
__global__ __launch_bounds__(256) void k_conv5(
    const __bf16* __restrict__ xh, const __bf16* __restrict__ wb,
    const float* __restrict__ bias, const float* __restrict__ bias2,
    float* __restrict__ outf, __bf16* __restrict__ outh,
    float* __restrict__ out2)
{
    constexpr int TW    = 20;
    constexpr int TH    = 12;            // 8 + 4 halo
    constexpr int NPIX  = TW * TH;       // 240
    constexpr int NPIX2 = NPIX / 2;      // 120
    constexpr int KK    = 25;
    constexpr int SLICE = 6144;          // 96 rows x 64B
    constexpr int MFT   = 5;

    __shared__ __align__(16) __bf16 lx[NPIX2 * 64];     // 15.36 KB
    __shared__ __align__(16) __bf16 lw[2][96 * 32];     // 12.29 KB
    __shared__ float lb[80];

    const int t    = threadIdx.x;
    const int w0   = blockIdx.x * 16, h0 = blockIdx.y * 8, b = blockIdx.z;
    const int wvv  = t >> 6;
    const int lane = t & 63;
    const int px   = lane & 15;
    const int g    = lane >> 4;

    auto STAGE = [&](int ci, int s, int buf) {
        const char* gs = (const char*)wb + (size_t)(ci * KK + s) * SLICE;
        if (wvv < 3) {
            #pragma unroll
            for (int r = 0; r < 2; ++r) {
                int ub = wvv * 128 + r * 64;
                gload_lds16(gs + (ub + lane) * 16, (char*)lw[buf] + ub * 16);
            }
        }
    };

    f32x4 acc[MFT][2];
    #pragma unroll
    for (int m = 0; m < MFT; ++m)
        #pragma unroll
        for (int nf = 0; nf < 2; ++nf)
            acc[m][nf] = (f32x4){0.f, 0.f, 0.f, 0.f};

    bf16x8 zv;
    #pragma unroll
    for (int j = 0; j < 8; ++j) zv[j] = (__bf16)0.f;

    for (int ci = 0; ci < 2; ++ci) {
        if (ci) __syncthreads();
        STAGE(ci, 0, 0);
        STAGE(ci, 1, 1);
        if (ci == 0) {
            if (t < 64) lb[t] = bias[t];
            if (t >= 64 && t < 80) lb[t] = (t - 64 < 9) ? bias2[t - 64] : 0.f;
        }

        // x-stage: 240 px x 4 c4-chunks = 960 elements
        #pragma unroll
        for (int xi = 0; xi < 4; ++xi) {
            int e = xi * 256 + t;
            if (e < NPIX * 4) {
                int pix = e >> 2, c4 = e & 3;
                int sy = pix / TW, sx = pix - sy * TW;
                int gy = h0 + sy - 2, gx = w0 + sx - 2;
                bool ok = (unsigned)gy < 256u && (unsigned)gx < 256u;
                bf16x8 v8 = zv;
                if (ok) v8 = *(const bf16x8*)(xh + ((((size_t)b << 16) + gy * 256 + gx) << 6)
                                              + ci * 32 + c4 * 8);
                int row = pix >> 1;
                int off = row * 128 + (((((pix & 1) << 2) + c4) ^ (row & 7)) << 4);
                *(bf16x8*)((char*)lx + off) = v8;
            }
        }
        __syncthreads();            // x + W slices 0,1 resident

        #pragma unroll
        for (int s = 0; s < KK; ++s) {
            const __bf16* lwb = (s & 1) ? lw[1] : lw[0];
            const int dx = s / 5, dy = s % 5;

            bf16x8 bfr[2];
            #pragma unroll
            for (int nf = 0; nf < 2; ++nf) {
                int pix = (wvv * 2 + nf + dy) * TW + (px + dx);
                int row = pix >> 1;
                int off = row * 128 + (((((pix & 1) << 2) + g) ^ (row & 7)) << 4);
                bfr[nf] = *(const bf16x8*)((const char*)lx + off);
            }
            bf16x8 afr[MFT];
            #pragma unroll
            for (int m = 0; m < MFT; ++m) {
                int o = m * 16 + px;
                int row = o >> 1;
                int off = row * 128 + (((((o & 1) << 2) + g) ^ (row & 7)) << 4);
                afr[m] = *(const bf16x8*)((const char*)lwb + off);
            }
            __builtin_amdgcn_s_setprio(1);
            #pragma unroll
            for (int m = 0; m < MFT; ++m)
                #pragma unroll
                for (int nf = 0; nf < 2; ++nf)
                    acc[m][nf] = __builtin_amdgcn_mfma_f32_16x16x32_bf16(
                        afr[m], bfr[nf], acc[m][nf], 0, 0, 0);
            __builtin_amdgcn_s_setprio(0);

            if (s == KK - 1) break;

            asm volatile("s_waitcnt lgkmcnt(0)" ::: "memory");
            __builtin_amdgcn_sched_barrier(0);
            __builtin_amdgcn_s_barrier();
            bool issued = (s + 2 < KK);
            if (issued) STAGE(ci, s + 2, s & 1);
            if (issued && wvv < 3) asm volatile("s_waitcnt vmcnt(2)" ::: "memory");
            else                   asm volatile("s_waitcnt vmcnt(0)" ::: "memory");
            __builtin_amdgcn_sched_barrier(0);
            __builtin_amdgcn_s_barrier();
        }
    }

    // epilogue: D row = g*4+j (+16*m), col = px; rows h0 + wvv*2 + nf
    #pragma unroll
    for (int m = 0; m < MFT; ++m) {
        #pragma unroll
        for (int nf = 0; nf < 2; ++nf) {
            int row = h0 + wvv * 2 + nf, col = w0 + px;
            if (m < 4) {
                float vj[4];
                #pragma unroll
                for (int j = 0; j < 4; ++j) {
                    float v = acc[m][nf][j] + lb[m * 16 + g * 4 + j];
                    vj[j] = v > 0.f ? v : 0.01f * v;
                }
                if constexpr (EPI == 0) {
                    bf16x4 pk;
                    #pragma unroll
                    for (int j = 0; j < 4; ++j) pk[j] = (__bf16)vj[j];
                    *(bf16x4*)(outh + ((((size_t)b << 16) + row * 256 + col) << 6)
                                    + m * 16 + g * 4) = pk;
                } else {
                    #pragma unroll
                    for (int j = 0; j < 4; ++j)
                        outf[((size_t)(b * 64 + m * 16 + g * 4 + j) << 16)
                             + row * 256 + col] = vj[j];
                }
            } else {
                #pragma unroll
                for (int j = 0; j < 4; ++j) {
                    int o2 = g * 4 + j;
                    if (o2 < 9)
                        out2[((size_t)(b * 9 + o2) << 16) + row * 256 + col]
                            = acc[m][nf][j] + lb[64 + o2];
                }
            }
        }
    }
}

// ---------------------------------------------------------------------------
// 3x3 MFMA conv, all-W staged per ci phase (no in-loop barriers), dx-outer
// register-blocked (r17 form, kept — ~9.5us). bf16 NHWC out.
// ---------------------------------------------------------------------------
__global__ __launch_bounds__(256) void k_conv3(
    const __bf16* __restrict__ xh, const __bf16* __restrict__ wb,
    const float* __restrict__ bias, __bf16* __restrict__ outh)
{
    constexpr int TW    = 18;
    constexpr int NPIX  = 324;
    constexpr int NPIX2 = 162;

    __shared__ __align__(16) __bf16 lx[NPIX2 * 64];
    __shared__ __align__(16) __bf16 lw[9 * 2048];
    __shared__ float lb[64];

    const int t    = threadIdx.x;
    const int w0   = blockIdx.x * 16, h0 = blockIdx.y * 16, b = blockIdx.z;
    const int wvv  = t >> 6;
    const int lane = t & 63;
    const int px   = lane & 15;
    const int g    = lane >> 4;

    f32x4 acc[4][4];
    #pragma unroll
    for (int m = 0; m < 4; ++m)
        #pragma unroll
        for (int nf = 0; nf < 4; ++nf)
            acc[m][nf] = (f32x4){0.f, 0.f, 0.f, 0.f};

    bf16x8 zv;
    #pragma unroll
    for (int j = 0; j < 8; ++j) zv[j] = (__bf16)0.f;

    for (int ci = 0; ci < 2; ++ci) {
        if (ci) __syncthreads();
        {
            const char* gs = (const char*)wb + (size_t)ci * 9 * 4096;
            #pragma unroll
            for (int r = 0; r < 9; ++r) {
                int ub = r * 256 + wvv * 64;
                gload_lds16(gs + (ub + lane) * 16, (char*)lw + ub * 16);
            }
        }
        if (ci == 0 && t < 64) lb[t] = bias[t];

        #pragma unroll
        for (int xi = 0; xi < 6; ++xi) {
            int e = xi * 256 + t;
            if (e < NPIX * 4) {
                int pix = e >> 2, c4 = e & 3;
                int sy = pix / TW, sx = pix - sy * TW;
                int gy = h0 + sy - 1, gx = w0 + sx - 1;
                bool ok = (unsigned)gy < 256u && (unsigned)gx < 256u;
                bf16x8 v8 = zv;
                if (ok) v8 = *(const bf16x8*)(xh + ((((size_t)b << 16) + gy * 256 + gx) << 6)
                                              + ci * 32 + c4 * 8);
                int row = pix >> 1;
                int off = row * 128 + (((((pix & 1) << 2) + c4) ^ (row & 7)) << 4);
                *(bf16x8*)((char*)lx + off) = v8;
            }
        }
        __syncthreads();

        #pragma unroll
        for (int dxg = 0; dxg < 3; ++dxg) {
            bf16x8 bfr[6];
            #pragma unroll
            for (int r = 0; r < 6; ++r) {
                int pix = (wvv * 4 + r) * TW + (px + dxg);
                int row = pix >> 1;
                int off = row * 128 + (((((pix & 1) << 2) + g) ^ (row & 7)) << 4);
                bfr[r] = *(const bf16x8*)((const char*)lx + off);
            }
            #pragma unroll
            for (int dy = 0; dy < 3; ++dy) {
                const __bf16* lwb = lw + (dxg * 3 + dy) * 2048;
                bf16x8 afr[4];
                #pragma unroll
                for (int m = 0; m < 4; ++m) {
                    int o = m * 16 + px;
                    int row = o >> 1;
                    int off = row * 128 + (((((o & 1) << 2) + g) ^ (row & 7)) << 4);
                    afr[m] = *(const bf16x8*)((const char*)lwb + off);
                }
                __builtin_amdgcn_s_setprio(1);
                #pragma unroll
                for (int m = 0; m < 4; ++m)
                    #pragma unroll
                    for (int nf = 0; nf < 4; ++nf)
                        acc[m][nf] = __builtin_amdgcn_mfma_f32_16x16x32_bf16(
                            afr[m], bfr[nf + dy], acc[m][nf], 0, 0, 0);
                __builtin_amdgcn_s_setprio(0);
            }
        }
    }

    #pragma unroll
    for (int m = 0; m < 4; ++m) {
        #pragma unroll
        for (int nf = 0; nf < 4; ++nf) {
            int row = h0 + wvv * 4 + nf, col = w0 + px;
            bf16x4 pk;
            #pragma unroll
            for (int j = 0; j < 4; ++j) {
                float v = acc[m][nf][j] + lb[m * 16 + g * 4 + j];
                pk[j] = (__bf16)v;
            }
            *(bf16x4*)(outh + ((((size_t)b << 16) + row * 256 + col) << 6)
                            + m * 16 + g * 4) = pk;
        }
    }
}

// ---------------------------------------------------------------------------
// 1x1 residual conv via MFMA -> bf16 NHWC.
// ---------------------------------------------------------------------------
__global__ __launch_bounds__(256) void k_conv1(
    const __bf16* __restrict__ xh, const __bf16* __restrict__ wb,
    const float* __restrict__ bias, __bf16* __restrict__ outh)
{
    constexpr int NPIX2 = 128;

    __shared__ __align__(16) __bf16 lx[NPIX2 * 64];
    __shared__ __align__(16) __bf16 lw[2048];
    __shared__ float lb[64];

    const int t    = threadIdx.x;
    const int w0   = blockIdx.x * 16, h0 = blockIdx.y * 16, b = blockIdx.z;
    const int wvv  = t >> 6;
    const int lane = t & 63;
    const int px   = lane & 15;
    const int g    = lane >> 4;

    f32x4 acc[4][4];
    #pragma unroll
    for (int m = 0; m < 4; ++m)
        #pragma unroll
        for (int nf = 0; nf < 4; ++nf)
            acc[m][nf] = (f32x4){0.f, 0.f, 0.f, 0.f};

    for (int ci = 0; ci < 2; ++ci) {
        if (ci) __syncthreads();
        {
            const char* gs = (const char*)wb + (size_t)ci * 4096;
            int ub = wvv * 64;
            gload_lds16(gs + (ub + lane) * 16, (char*)lw + ub * 16);
        }
        if (ci == 0 && t < 64) lb[t] = bias[t];

        #pragma unroll
        for (int xi = 0; xi < 4; ++xi) {
            int e = xi * 256 + t;
            int pix = e >> 2, c4 = e & 3;
            int gy = h0 + (pix >> 4), gx = w0 + (pix & 15);
            bf16x8 v8 = *(const bf16x8*)(xh + ((((size_t)b << 16) + gy * 256 + gx) << 6)
                                         + ci * 32 + c4 * 8);
            int row = pix >> 1;
            int off = row * 128 + (((((pix & 1) << 2) + c4) ^ (row & 7)) << 4);
            *(bf16x8*)((char*)lx + off) = v8;
        }
        __syncthreads();

        bf16x8 bfr[4];
        #pragma unroll
        for (int nf = 0; nf < 4; ++nf) {
            int pix = (wvv * 4 + nf) * 16 + px;
            int row = pix >> 1;
            int off = row * 128 + (((((pix & 1) << 2) + g) ^ (row & 7)) << 4);
            bfr[nf] = *(const bf16x8*)((const char*)lx + off);
        }
        bf16x8 afr[4];
        #pragma unroll
        for (int m = 0; m < 4; ++m) {
            int o = m * 16 + px;
            int row = o >> 1;
            int off = row * 128 + (((((o & 1) << 2) + g) ^ (row & 7)) << 4);
            afr[m] = *(const bf16x8*)((const char*)lw + off);
        }
        #pragma unroll
        for (int m = 0; m < 4; ++m)
            #pragma unroll
            for (int nf = 0; nf < 4; ++nf)
                acc[m][nf] = __builtin_amdgcn_mfma_f32_16x16x32_bf16(
                    afr[m], bfr[nf], acc[m][nf], 0, 0, 0);
    }

    #pragma unroll
    for (int m = 0; m < 4; ++m) {
        #pragma unroll
        for (int nf = 0; nf < 4; ++nf) {
            int row = h0 + wvv * 4 + nf, col = w0 + px;
            bf16x4 pk;
            #pragma unroll
            for (int j = 0; j < 4; ++j)
                pk[j] = (__bf16)(acc[m][nf][j] + lb[m * 16 + g * 4 + j]);
            *(bf16x4*)(outh + ((((size_t)b << 16) + row * 256 + col) << 6)
                            + m * 16 + g * 4) = pk;
        }
    }
}

// ---------------------------------------------------------------------------
// Adaptive einsum, coalesced: 8 threads/pixel. -> bf16 NHWC.
// ---------------------------------------------------------------------------
__global__ __launch_bounds__(256, 4) void k_ada1(
    const float* __restrict__ wgt, const __bf16* __restrict__ xin,
    __bf16* __restrict__ outh)
{
    int t  = threadIdx.x;
    int pg = t >> 3, c8 = t & 7;
    int p  = blockIdx.x * 32 + pg;
    int b  = p >> 16, hw = p & 65535;
    int h  = hw >> 8, wc = hw & 255;

    const float* wp = wgt + ((size_t)(b * 9) << 16) + hw;
    const __bf16* cen = xin + (size_t)p * 64 + c8 * 8;

    float wk[9];
    const __bf16* nbp[9];
    #pragma unroll
    for (int dy = 0; dy < 3; ++dy)
        #pragma unroll
        for (int dx = 0; dx < 3; ++dx) {
            int k = dy * 3 + dx;
            bool ok = ((unsigned)(h + dy - 1) < 256u) &&
                      ((unsigned)(wc + dx - 1) < 256u);
            wk[k]  = ok ? wp[(size_t)k << 16] : 0.f;
            nbp[k] = ok ? cen + ((dy - 1) * 256 + (dx - 1)) * 64 : cen;
        }

    float acc[8] = {0.f,0.f,0.f,0.f,0.f,0.f,0.f,0.f};
    #pragma unroll
    for (int k = 0; k < 9; ++k) {
        bf16x8 v8 = *(const bf16x8*)nbp[k];
        float w = wk[k];
        #pragma unroll
        for (int j = 0; j < 8; ++j) acc[j] += w * (float)v8[j];
    }

    bf16x8 o8;
    #pragma unroll
    for (int j = 0; j < 8; ++j) {
        float v = acc[j];
        o8[j] = (__bf16)(v > 0.f ? v : 0.01f * v);
    }
    *(bf16x8*)(outh + (size_t)p * 64 + c8 * 8) = o8;
}

// ---------------------------------------------------------------------------
// Final adaptive einsum: lrelu(ada) + res (bf16 NHWC), pure-write f32 NCHW.
// ---------------------------------------------------------------------------
__global__ __launch_bounds__(256, 4) void k_ada2(
    const float* __restrict__ wgt, const __bf16* __restrict__ x2h,
    const __bf16* __restrict__ resh, float* __restrict__ outf)
{
    __shared__ float ls[32 * 65];

    int t  = threadIdx.x;
    int pg = t >> 3, c8 = t & 7;
    int p  = blockIdx.x * 32 + pg;
    int b  = p >> 16, hw = p & 65535;
    int h  = hw >> 8, wc = hw & 255;

    const float* wp = wgt + ((size_t)(b * 9) << 16) + hw;
    const __bf16* cen = x2h + (size_t)p * 64 + c8 * 8;

    float wk[9];
    const __bf16* nbp[9];
    #pragma unroll
    for (int dy = 0; dy < 3; ++dy)
        #pragma unroll
        for (int dx = 0; dx < 3; ++dx) {
            int k = dy * 3 + dx;
            bool ok = ((unsigned)(h + dy - 1) < 256u) &&
                      ((unsigned)(wc + dx - 1) < 256u);
            wk[k]  = ok ? wp[(size_t)k << 16] : 0.f;
            nbp[k] = ok ? cen + ((dy - 1) * 256 + (dx - 1)) * 64 : cen;
        }

    float acc[8] = {0.f,0.f,0.f,0.f,0.f,0.f,0.f,0.f};
    #pragma unroll
    for (int k = 0; k < 9; ++k) {
        bf16x8 v8 = *(const bf16x8*)nbp[k];
        float w = wk[k];
        #pragma unroll
        for (int j = 0; j < 8; ++j) acc[j] += w * (float)v8[j];
    }

    bf16x8 r8 = *(const bf16x8*)(resh + (size_t)p * 64 + c8 * 8);
    #pragma unroll
    for (int j = 0; j < 8; ++j) {
        float v = acc[j];
        v = v > 0.f ? v : 0.01f * v;
        ls[pg * 65 + c8 * 8 + j] = v + (float)r8[j];
    }
    __syncthreads();

    int pbase = blockIdx.x * 32;
    int bb    = pbase >> 16, hwb = pbase & 65535;
    int pix   = t & 31, cq = t >> 5;
    #pragma unroll
    for (int i = 0; i < 8; ++i) {
        int c = i * 8 + cq;
        size_t oi = ((size_t)(bb * 64 + c) << 16) + hwb + pix;
        outf[oi] = ls[pix * 65 + c];
    }
}

// ---------------------------------------------------------------------------
// Buffer plan (ws use = 55.8 MB):
//   wgt   f32  @0           4,718,592   adaptive weights (F1->ada1, F2->ada2)
//   xh    bf16 @4,718,592  16,777,216   x NHWC
//   mh    bf16 @21,495,808 16,777,216   mask NHWC; x2h reuses after F1
//   wb    bf16 @38,273,024    770,048   prepped conv weights (dx-major)
//   resh  bf16 @39,043,072 16,777,216   residual, bf16 NHWC (conv1 -> ada2)
// d_out scratch: out_x lower = maska_h, out_x upper = xa_h, out_m = x1_h.
// Launches: prep -> F1 -> c3_1 -> ada1 -> F2 -> c3_2 -> conv1 -> ada2.
// ---------------------------------------------------------------------------
extern "C" void kernel_launch(void* const* d_in, const int* in_sizes, int n_in,
                              void* d_out, int out_size, void* d_ws, size_t ws_size,
                              hipStream_t stream)
{
    const float* x     = (const float*)d_in[0];
    const float* mask  = (const float*)d_in[1];
    const float* aw1_w = (const float*)d_in[2];
    const float* aw1_b = (const float*)d_in[3];
    const float* mt1_w = (const float*)d_in[4];
    const float* mt1_b = (const float*)d_in[5];
    const float* c1_w  = (const float*)d_in[6];
    const float* c1_b  = (const float*)d_in[7];
    const float* aw2_w = (const float*)d_in[8];
    const float* aw2_b = (const float*)d_in[9];
    const float* mt2_w = (const float*)d_in[10];
    const float* mt2_b = (const float*)d_in[11];
    const float* c2_w  = (const float*)d_in[12];
    const float* c2_b  = (const float*)d_in[13];
    const float* cr_w  = (const float*)d_in[14];
    const float* cr_b  = (const float*)d_in[15];

    float* out_x = (float*)d_out;
    float* out_m = (float*)d_out + 8388608;

    float*  wgt   = (float*)d_ws;
    __bf16* xh    = (__bf16*)((char*)d_ws + 4718592);
    __bf16* mh    = (__bf16*)((char*)d_ws + 21495808);
    __bf16* x2h   = mh;                                // sequential live ranges
    __bf16* wbase = (__bf16*)((char*)d_ws + 38273024);
    __bf16* wb_c1 = wbase;             // 36864 elems
    __bf16* wb_c2 = wbase + 36864;     // 36864
    __bf16* wb_F1 = wbase + 73728;     // 153600
    __bf16* wb_F2 = wbase + 227328;    // 153600
    __bf16* wb_cr = wbase + 380928;    // 4096
    __bf16* resh  = (__bf16*)((char*)d_ws + 39043072);

    __bf16* maska_h = (__bf16*)out_x;               // lower 16.78 MB
    __bf16* xa_h    = (__bf16*)out_x + 8388608;     // upper 16.78 MB
    __bf16* x1_h    = (__bf16*)out_m;               // lower 16.78 MB

    dim3 blk(256);
    dim3 gconv5(16, 32, 2);
    dim3 gconv(16, 16, 2);
    dim3 gada(4096);

    // 0. merged prep
    k_prep<<<dim3(2528), blk, 0, stream>>>(x, mask, c1_w, c2_w,
        mt1_w, aw1_w, mt2_w, aw2_w, cr_w,
        xh, mh, wb_c1, wb_c2, wb_F1, wb_F2, wb_cr);

    // 1. F1(mh): maska = lrelu(mt1) -> maska_h (bf16), weight1 = aw1 -> wgt
    k_conv5<0><<<gconv5, blk, 0, stream>>>(mh, wb_F1, mt1_b, aw1_b,
                                           nullptr, maska_h, wgt);
    // 2. x1 = conv3x3(xh, c1) -> x1_h
    k_conv3<<<gconv, blk, 0, stream>>>(xh, wb_c1, c1_b, x1_h);
    // 3. xa = lrelu(ada(wgt, x1)) -> xa_h
    k_ada1<<<gada, blk, 0, stream>>>(wgt, x1_h, xa_h);
    // 4. F2(maska_h): final mask = lrelu(mt2) -> out_m (f32), weight2 -> wgt
    k_conv5<1><<<gconv5, blk, 0, stream>>>(maska_h, wb_F2, mt2_b, aw2_b,
                                           out_m, nullptr, wgt);
    // 5. x2 = conv3x3(xa_h, c2) -> x2h
    k_conv3<<<gconv, blk, 0, stream>>>(xa_h, wb_c2, c2_b, x2h);
    // 6. res = conv1x1(xh) via MFMA -> resh (bf16 NHWC)
    k_conv1<<<gconv, blk, 0, stream>>>(xh, wb_cr, cr_b, resh);
    // 7. out_x = lrelu(ada(wgt, x2)) + res   (pure write)
    k_ada2<<<gada, blk, 0, stream>>>(wgt, x2h, resh, out_x);
}

// Round 19
// 167.243 us; speedup vs baseline: 1.1137x; 1.1137x over previous
//
#include <hip/hip_runtime.h>

#define HWSZ 65536   // 256*256
#define CCH  64

typedef __bf16 bf16x8 __attribute__((ext_vector_type(8)));
typedef __bf16 bf16x4 __attribute__((ext_vector_type(4)));
typedef float  f32x4  __attribute__((ext_vector_type(4)));

__device__ inline void gload_lds16(const void* g, void* l) {
    __builtin_amdgcn_global_load_lds(
        (const __attribute__((address_space(1))) void*)g,
        (__attribute__((address_space(3))) void*)l, 16, 0, 0);
}

// ===========================================================================
// Prep bodies (one launch). W layouts: ci-split + 2-rows-per-128B packed +
// inverse-swizzled. prep3 = DX-MAJOR slice order (for conv3's dx-outer
// loop); prepF/prep1 = natural k order (for conv5's per-slice pipeline).
// ===========================================================================

__device__ void cvt_body(int cb, const float* __restrict__ src,
                         __bf16* __restrict__ dst)
{
    int p  = cb * 256 + threadIdx.x;
    int b  = p >> 16, hw = p & 65535;
    const float* sp = src + (((size_t)b * 64) << 16) + hw;
    __bf16* dp = dst + (size_t)p * 64;
    #pragma unroll
    for (int c8 = 0; c8 < 8; ++c8) {
        bf16x8 v8;
        #pragma unroll
        for (int j = 0; j < 8; ++j)
            v8[j] = (__bf16)sp[(size_t)(c8 * 8 + j) << 16];
        *(bf16x8*)(dp + c8 * 8) = v8;
    }
}

__device__ void prep3_body(int cb, const float* __restrict__ src,
                           __bf16* __restrict__ dst)
{
    int t = cb * 256 + threadIdx.x;
    if (t >= 2 * 9 * 2048) return;
    int j  = t & 7;
    int u  = (t >> 3) & 255;
    int q  = t >> 11;
    int s  = q % 9, ci = q / 9;
    int dx = s / 3, dy = s % 3;
    int k  = dy * 3 + dx;              // dx-major slice order
    int r  = u >> 3;
    int v  = (u & 7) ^ (r & 7);
    int o  = 2 * r + (v >> 2);
    int g  = v & 3;
    int i  = ci * 32 + g * 8 + j;
    dst[t] = (__bf16)src[((size_t)o * 64 + i) * 9 + k];
}

__device__ void prep1_body(int cb, const float* __restrict__ src,
                           __bf16* __restrict__ dst)
{
    int t = cb * 256 + threadIdx.x;
    if (t >= 2 * 2048) return;
    int j  = t & 7;
    int u  = (t >> 3) & 255;
    int ci = t >> 11;
    int r  = u >> 3;
    int v  = (u & 7) ^ (r & 7);
    int o  = 2 * r + (v >> 2);
    int g  = v & 3;
    int i  = ci * 32 + g * 8 + j;
    dst[t] = (__bf16)src[(size_t)o * 64 + i];
}

__device__ void prepF_body(int cb, const float* __restrict__ mt,
                           const float* __restrict__ aw, __bf16* __restrict__ dst)
{
    int t = cb * 256 + threadIdx.x;
    if (t >= 2 * 25 * 3072) return;
    int j  = t & 7;
    int u  = (t >> 3) % 384;
    int q  = t / 3072;
    int k  = q % 25, ci = q / 25;      // natural k order
    int r  = u >> 3;
    int v  = (u & 7) ^ (r & 7);
    int o  = 2 * r + (v >> 2);
    int g  = v & 3;
    int i  = ci * 32 + g * 8 + j;
    float val = 0.f;
    if (o < 64)      val = mt[((size_t)o * 64 + i) * 25 + k];
    else if (o < 73) val = aw[((size_t)(o - 64) * 64 + i) * 25 + k];
    dst[t] = (__bf16)val;
}

// prep super-kernel. Grid 2528.
__global__ __launch_bounds__(256) void k_prep(
    const float* x, const float* mask,
    const float* c1w, const float* c2w,
    const float* mt1w, const float* aw1w,
    const float* mt2w, const float* aw2w,
    const float* crw,
    __bf16* xh, __bf16* mh,
    __bf16* wbc1, __bf16* wbc2, __bf16* wbF1, __bf16* wbF2, __bf16* wbcr)
{
    int bid = blockIdx.x;
    if      (bid < 512)  cvt_body(bid, x, xh);
    else if (bid < 1024) cvt_body(bid - 512, mask, mh);
    else if (bid < 1168) prep3_body(bid - 1024, c1w, wbc1);
    else if (bid < 1312) prep3_body(bid - 1168, c2w, wbc2);
    else if (bid < 1912) prepF_body(bid - 1312, mt1w, aw1w, wbF1);
    else if (bid < 2512) prepF_body(bid - 1912, mt2w, aw2w, wbF2);
    else                 prep1_body(bid - 2512, crw, wbcr);
}

// ---------------------------------------------------------------------------
// Fused 5x5 MFMA conv (round-15 proven form, 40us): 16x16 tile, ci-split,
// per-slice double-buffered async W staging, counted vmcnt, raw barriers,
// setprio. EPI=0: bf16 NHWC; EPI=1: f32 NCHW. aw -> out2 f32 NCHW.
// ---------------------------------------------------------------------------
template<int EPI>
__global__ __launch_bounds__(256) void k_conv5(
    const __bf16* __restrict__ xh, const __bf16* __restrict__ wb,
    const float* __restrict__ bias, const float* __restrict__ bias2,
    float* __restrict__ outf, __bf16* __restrict__ outh,
    float* __restrict__ out2)
{
    constexpr int TW    = 20;
    constexpr int NPIX  = 400;
    constexpr int KK    = 25;
    constexpr int SROWS = 96;
    constexpr int SLICE = SROWS * 64;
    constexpr int NPIX2 = NPIX / 2;
    constexpr int MFT   = 5;

    __shared__ __align__(16) __bf16 lx[NPIX2 * 64];
    __shared__ __align__(16) __bf16 lw[2][SROWS * 32];
    __shared__ float lb[80];

    const int t    = threadIdx.x;
    const int w0   = blockIdx.x * 16, h0 = blockIdx.y * 16, b = blockIdx.z;
    const int wvv  = t >> 6;
    const int lane = t & 63;
    const int px   = lane & 15;
    const int g    = lane >> 4;

    auto STAGE = [&](int ci, int k, int buf) {
        const char* gs = (const char*)wb + (size_t)(ci * KK + k) * SLICE;
        if (wvv < 3) {
            #pragma unroll
            for (int r = 0; r < 2; ++r) {
                int ub = wvv * 128 + r * 64;
                gload_lds16(gs + (ub + lane) * 16, (char*)lw[buf] + ub * 16);
            }
        }
    };

    f32x4 acc[MFT][4];
    #pragma unroll
    for (int m = 0; m < MFT; ++m)
        #pragma unroll
        for (int nf = 0; nf < 4; ++nf)
            acc[m][nf] = (f32x4){0.f, 0.f, 0.f, 0.f};

    bf16x8 zv;
    #pragma unroll
    for (int j = 0; j < 8; ++j) zv[j] = (__bf16)0.f;

    for (int ci = 0; ci < 2; ++ci) {
        if (ci) __syncthreads();
        STAGE(ci, 0, 0);
        STAGE(ci, 1, 1);
        if (ci == 0) {
            if (t < 64) lb[t] = bias[t];
            if (t >= 64 && t < 80) lb[t] = (t - 64 < 9) ? bias2[t - 64] : 0.f;
        }

        #pragma unroll
        for (int xi = 0; xi < 7; ++xi) {
            int e = xi * 256 + t;
            if (e < NPIX * 4) {
                int pix = e >> 2, c4 = e & 3;
                int sy = pix / TW, sx = pix - sy * TW;
                int gy = h0 + sy - 2, gx = w0 + sx - 2;
                bool ok = (unsigned)gy < 256u && (unsigned)gx < 256u;
                bf16x8 v8 = zv;
                if (ok) v8 = *(const bf16x8*)(xh + ((((size_t)b << 16) + gy * 256 + gx) << 6)
                                              + ci * 32 + c4 * 8);
                int row = pix >> 1;
                int off = row * 128 + (((((pix & 1) << 2) + c4) ^ (row & 7)) << 4);
                *(bf16x8*)((char*)lx + off) = v8;
            }
        }
        __syncthreads();

        #pragma unroll
        for (int k = 0; k < KK; ++k) {
            const __bf16* lwb = (k & 1) ? lw[1] : lw[0];
            const int dy = k / 5, dx = k - dy * 5;

            bf16x8 bfr[4];
            #pragma unroll
            for (int nf = 0; nf < 4; ++nf) {
                int pix = (wvv * 4 + nf + dy) * TW + (px + dx);
                int row = pix >> 1;
                int off = row * 128 + (((((pix & 1) << 2) + g) ^ (row & 7)) << 4);
                bfr[nf] = *(const bf16x8*)((const char*)lx + off);
            }
            bf16x8 afr[MFT];
            #pragma unroll
            for (int m = 0; m < MFT; ++m) {
                int o = m * 16 + px;
                int row = o >> 1;
                int off = row * 128 + (((((o & 1) << 2) + g) ^ (row & 7)) << 4);
                afr[m] = *(const bf16x8*)((const char*)lwb + off);
            }
            __builtin_amdgcn_s_setprio(1);
            #pragma unroll
            for (int m = 0; m < MFT; ++m)
                #pragma unroll
                for (int nf = 0; nf < 4; ++nf)
                    acc[m][nf] = __builtin_amdgcn_mfma_f32_16x16x32_bf16(
                        afr[m], bfr[nf], acc[m][nf], 0, 0, 0);
            __builtin_amdgcn_s_setprio(0);

            if (k == KK - 1) break;

            asm volatile("s_waitcnt lgkmcnt(0)" ::: "memory");
            __builtin_amdgcn_sched_barrier(0);
            __builtin_amdgcn_s_barrier();
            bool issued = (k + 2 < KK);
            if (issued) STAGE(ci, k + 2, k & 1);
            if (issued && wvv < 3) asm volatile("s_waitcnt vmcnt(2)" ::: "memory");
            else                   asm volatile("s_waitcnt vmcnt(0)" ::: "memory");
            __builtin_amdgcn_sched_barrier(0);
            __builtin_amdgcn_s_barrier();
        }
    }

    // epilogue: D row = g*4+j (+16*m), col = px
    #pragma unroll
    for (int m = 0; m < MFT; ++m) {
        #pragma unroll
        for (int nf = 0; nf < 4; ++nf) {
            int row = h0 + wvv * 4 + nf, col = w0 + px;
            if (m < 4) {
                float vj[4];
                #pragma unroll
                for (int j = 0; j < 4; ++j) {
                    float v = acc[m][nf][j] + lb[m * 16 + g * 4 + j];
                    vj[j] = v > 0.f ? v : 0.01f * v;
                }
                if constexpr (EPI == 0) {
                    bf16x4 pk;
                    #pragma unroll
                    for (int j = 0; j < 4; ++j) pk[j] = (__bf16)vj[j];
                    *(bf16x4*)(outh + ((((size_t)b << 16) + row * 256 + col) << 6)
                                    + m * 16 + g * 4) = pk;
                } else {
                    #pragma unroll
                    for (int j = 0; j < 4; ++j)
                        outf[((size_t)(b * 64 + m * 16 + g * 4 + j) << 16)
                             + row * 256 + col] = vj[j];
                }
            } else {
                #pragma unroll
                for (int j = 0; j < 4; ++j) {
                    int o2 = g * 4 + j;
                    if (o2 < 9)
                        out2[((size_t)(b * 9 + o2) << 16) + row * 256 + col]
                            = acc[m][nf][j] + lb[64 + o2];
                }
            }
        }
    }
}

// ---------------------------------------------------------------------------
// 3x3 MFMA conv (round-17 form, kept): all-W staged per ci phase, no in-loop
// barriers, dx-outer register-blocked B reads. bf16 NHWC out.
// ---------------------------------------------------------------------------
__global__ __launch_bounds__(256) void k_conv3(
    const __bf16* __restrict__ xh, const __bf16* __restrict__ wb,
    const float* __restrict__ bias, __bf16* __restrict__ outh)
{
    constexpr int TW    = 18;
    constexpr int NPIX  = 324;
    constexpr int NPIX2 = 162;

    __shared__ __align__(16) __bf16 lx[NPIX2 * 64];
    __shared__ __align__(16) __bf16 lw[9 * 2048];
    __shared__ float lb[64];

    const int t    = threadIdx.x;
    const int w0   = blockIdx.x * 16, h0 = blockIdx.y * 16, b = blockIdx.z;
    const int wvv  = t >> 6;
    const int lane = t & 63;
    const int px   = lane & 15;
    const int g    = lane >> 4;

    f32x4 acc[4][4];
    #pragma unroll
    for (int m = 0; m < 4; ++m)
        #pragma unroll
        for (int nf = 0; nf < 4; ++nf)
            acc[m][nf] = (f32x4){0.f, 0.f, 0.f, 0.f};

    bf16x8 zv;
    #pragma unroll
    for (int j = 0; j < 8; ++j) zv[j] = (__bf16)0.f;

    for (int ci = 0; ci < 2; ++ci) {
        if (ci) __syncthreads();
        {
            const char* gs = (const char*)wb + (size_t)ci * 9 * 4096;
            #pragma unroll
            for (int r = 0; r < 9; ++r) {
                int ub = r * 256 + wvv * 64;
                gload_lds16(gs + (ub + lane) * 16, (char*)lw + ub * 16);
            }
        }
        if (ci == 0 && t < 64) lb[t] = bias[t];

        #pragma unroll
        for (int xi = 0; xi < 6; ++xi) {
            int e = xi * 256 + t;
            if (e < NPIX * 4) {
                int pix = e >> 2, c4 = e & 3;
                int sy = pix / TW, sx = pix - sy * TW;
                int gy = h0 + sy - 1, gx = w0 + sx - 1;
                bool ok = (unsigned)gy < 256u && (unsigned)gx < 256u;
                bf16x8 v8 = zv;
                if (ok) v8 = *(const bf16x8*)(xh + ((((size_t)b << 16) + gy * 256 + gx) << 6)
                                              + ci * 32 + c4 * 8);
                int row = pix >> 1;
                int off = row * 128 + (((((pix & 1) << 2) + c4) ^ (row & 7)) << 4);
                *(bf16x8*)((char*)lx + off) = v8;
            }
        }
        __syncthreads();

        #pragma unroll
        for (int dxg = 0; dxg < 3; ++dxg) {
            bf16x8 bfr[6];
            #pragma unroll
            for (int r = 0; r < 6; ++r) {
                int pix = (wvv * 4 + r) * TW + (px + dxg);
                int row = pix >> 1;
                int off = row * 128 + (((((pix & 1) << 2) + g) ^ (row & 7)) << 4);
                bfr[r] = *(const bf16x8*)((const char*)lx + off);
            }
            #pragma unroll
            for (int dy = 0; dy < 3; ++dy) {
                const __bf16* lwb = lw + (dxg * 3 + dy) * 2048;
                bf16x8 afr[4];
                #pragma unroll
                for (int m = 0; m < 4; ++m) {
                    int o = m * 16 + px;
                    int row = o >> 1;
                    int off = row * 128 + (((((o & 1) << 2) + g) ^ (row & 7)) << 4);
                    afr[m] = *(const bf16x8*)((const char*)lwb + off);
                }
                __builtin_amdgcn_s_setprio(1);
                #pragma unroll
                for (int m = 0; m < 4; ++m)
                    #pragma unroll
                    for (int nf = 0; nf < 4; ++nf)
                        acc[m][nf] = __builtin_amdgcn_mfma_f32_16x16x32_bf16(
                            afr[m], bfr[nf + dy], acc[m][nf], 0, 0, 0);
                __builtin_amdgcn_s_setprio(0);
            }
        }
    }

    #pragma unroll
    for (int m = 0; m < 4; ++m) {
        #pragma unroll
        for (int nf = 0; nf < 4; ++nf) {
            int row = h0 + wvv * 4 + nf, col = w0 + px;
            bf16x4 pk;
            #pragma unroll
            for (int j = 0; j < 4; ++j) {
                float v = acc[m][nf][j] + lb[m * 16 + g * 4 + j];
                pk[j] = (__bf16)v;
            }
            *(bf16x4*)(outh + ((((size_t)b << 16) + row * 256 + col) << 6)
                            + m * 16 + g * 4) = pk;
        }
    }
}

// ---------------------------------------------------------------------------
// 1x1 residual conv via MFMA -> bf16 NHWC.
// ---------------------------------------------------------------------------
__global__ __launch_bounds__(256) void k_conv1(
    const __bf16* __restrict__ xh, const __bf16* __restrict__ wb,
    const float* __restrict__ bias, __bf16* __restrict__ outh)
{
    constexpr int NPIX2 = 128;

    __shared__ __align__(16) __bf16 lx[NPIX2 * 64];
    __shared__ __align__(16) __bf16 lw[2048];
    __shared__ float lb[64];

    const int t    = threadIdx.x;
    const int w0   = blockIdx.x * 16, h0 = blockIdx.y * 16, b = blockIdx.z;
    const int wvv  = t >> 6;
    const int lane = t & 63;
    const int px   = lane & 15;
    const int g    = lane >> 4;

    f32x4 acc[4][4];
    #pragma unroll
    for (int m = 0; m < 4; ++m)
        #pragma unroll
        for (int nf = 0; nf < 4; ++nf)
            acc[m][nf] = (f32x4){0.f, 0.f, 0.f, 0.f};

    for (int ci = 0; ci < 2; ++ci) {
        if (ci) __syncthreads();
        {
            const char* gs = (const char*)wb + (size_t)ci * 4096;
            int ub = wvv * 64;
            gload_lds16(gs + (ub + lane) * 16, (char*)lw + ub * 16);
        }
        if (ci == 0 && t < 64) lb[t] = bias[t];

        #pragma unroll
        for (int xi = 0; xi < 4; ++xi) {
            int e = xi * 256 + t;
            int pix = e >> 2, c4 = e & 3;
            int gy = h0 + (pix >> 4), gx = w0 + (pix & 15);
            bf16x8 v8 = *(const bf16x8*)(xh + ((((size_t)b << 16) + gy * 256 + gx) << 6)
                                         + ci * 32 + c4 * 8);
            int row = pix >> 1;
            int off = row * 128 + (((((pix & 1) << 2) + c4) ^ (row & 7)) << 4);
            *(bf16x8*)((char*)lx + off) = v8;
        }
        __syncthreads();

        bf16x8 bfr[4];
        #pragma unroll
        for (int nf = 0; nf < 4; ++nf) {
            int pix = (wvv * 4 + nf) * 16 + px;
            int row = pix >> 1;
            int off = row * 128 + (((((pix & 1) << 2) + g) ^ (row & 7)) << 4);
            bfr[nf] = *(const bf16x8*)((const char*)lx + off);
        }
        bf16x8 afr[4];
        #pragma unroll
        for (int m = 0; m < 4; ++m) {
            int o = m * 16 + px;
            int row = o >> 1;
            int off = row * 128 + (((((o & 1) << 2) + g) ^ (row & 7)) << 4);
            afr[m] = *(const bf16x8*)((const char*)lw + off);
        }
        #pragma unroll
        for (int m = 0; m < 4; ++m)
            #pragma unroll
            for (int nf = 0; nf < 4; ++nf)
                acc[m][nf] = __builtin_amdgcn_mfma_f32_16x16x32_bf16(
                    afr[m], bfr[nf], acc[m][nf], 0, 0, 0);
    }

    #pragma unroll
    for (int m = 0; m < 4; ++m) {
        #pragma unroll
        for (int nf = 0; nf < 4; ++nf) {
            int row = h0 + wvv * 4 + nf, col = w0 + px;
            bf16x4 pk;
            #pragma unroll
            for (int j = 0; j < 4; ++j)
                pk[j] = (__bf16)(acc[m][nf][j] + lb[m * 16 + g * 4 + j]);
            *(bf16x4*)(outh + ((((size_t)b << 16) + row * 256 + col) << 6)
                            + m * 16 + g * 4) = pk;
        }
    }
}

// ---------------------------------------------------------------------------
// Adaptive einsum, coalesced: 8 threads/pixel. -> bf16 NHWC.
// ---------------------------------------------------------------------------
__global__ __launch_bounds__(256, 4) void k_ada1(
    const float* __restrict__ wgt, const __bf16* __restrict__ xin,
    __bf16* __restrict__ outh)
{
    int t  = threadIdx.x;
    int pg = t >> 3, c8 = t & 7;
    int p  = blockIdx.x * 32 + pg;
    int b  = p >> 16, hw = p & 65535;
    int h  = hw >> 8, wc = hw & 255;

    const float* wp = wgt + ((size_t)(b * 9) << 16) + hw;
    const __bf16* cen = xin + (size_t)p * 64 + c8 * 8;

    float wk[9];
    const __bf16* nbp[9];
    #pragma unroll
    for (int dy = 0; dy < 3; ++dy)
        #pragma unroll
        for (int dx = 0; dx < 3; ++dx) {
            int k = dy * 3 + dx;
            bool ok = ((unsigned)(h + dy - 1) < 256u) &&
                      ((unsigned)(wc + dx - 1) < 256u);
            wk[k]  = ok ? wp[(size_t)k << 16] : 0.f;
            nbp[k] = ok ? cen + ((dy - 1) * 256 + (dx - 1)) * 64 : cen;
        }

    float acc[8] = {0.f,0.f,0.f,0.f,0.f,0.f,0.f,0.f};
    #pragma unroll
    for (int k = 0; k < 9; ++k) {
        bf16x8 v8 = *(const bf16x8*)nbp[k];
        float w = wk[k];
        #pragma unroll
        for (int j = 0; j < 8; ++j) acc[j] += w * (float)v8[j];
    }

    bf16x8 o8;
    #pragma unroll
    for (int j = 0; j < 8; ++j) {
        float v = acc[j];
        o8[j] = (__bf16)(v > 0.f ? v : 0.01f * v);
    }
    *(bf16x8*)(outh + (size_t)p * 64 + c8 * 8) = o8;
}

// ---------------------------------------------------------------------------
// Final adaptive einsum: lrelu(ada) + res (bf16 NHWC), pure-write f32 NCHW.
// ---------------------------------------------------------------------------
__global__ __launch_bounds__(256, 4) void k_ada2(
    const float* __restrict__ wgt, const __bf16* __restrict__ x2h,
    const __bf16* __restrict__ resh, float* __restrict__ outf)
{
    __shared__ float ls[32 * 65];

    int t  = threadIdx.x;
    int pg = t >> 3, c8 = t & 7;
    int p  = blockIdx.x * 32 + pg;
    int b  = p >> 16, hw = p & 65535;
    int h  = hw >> 8, wc = hw & 255;

    const float* wp = wgt + ((size_t)(b * 9) << 16) + hw;
    const __bf16* cen = x2h + (size_t)p * 64 + c8 * 8;

    float wk[9];
    const __bf16* nbp[9];
    #pragma unroll
    for (int dy = 0; dy < 3; ++dy)
        #pragma unroll
        for (int dx = 0; dx < 3; ++dx) {
            int k = dy * 3 + dx;
            bool ok = ((unsigned)(h + dy - 1) < 256u) &&
                      ((unsigned)(wc + dx - 1) < 256u);
            wk[k]  = ok ? wp[(size_t)k << 16] : 0.f;
            nbp[k] = ok ? cen + ((dy - 1) * 256 + (dx - 1)) * 64 : cen;
        }

    float acc[8] = {0.f,0.f,0.f,0.f,0.f,0.f,0.f,0.f};
    #pragma unroll
    for (int k = 0; k < 9; ++k) {
        bf16x8 v8 = *(const bf16x8*)nbp[k];
        float w = wk[k];
        #pragma unroll
        for (int j = 0; j < 8; ++j) acc[j] += w * (float)v8[j];
    }

    bf16x8 r8 = *(const bf16x8*)(resh + (size_t)p * 64 + c8 * 8);
    #pragma unroll
    for (int j = 0; j < 8; ++j) {
        float v = acc[j];
        v = v > 0.f ? v : 0.01f * v;
        ls[pg * 65 + c8 * 8 + j] = v + (float)r8[j];
    }
    __syncthreads();

    int pbase = blockIdx.x * 32;
    int bb    = pbase >> 16, hwb = pbase & 65535;
    int pix   = t & 31, cq = t >> 5;
    #pragma unroll
    for (int i = 0; i < 8; ++i) {
        int c = i * 8 + cq;
        size_t oi = ((size_t)(bb * 64 + c) << 16) + hwb + pix;
        outf[oi] = ls[pix * 65 + c];
    }
}

// ---------------------------------------------------------------------------
// Buffer plan (ws use = 55.8 MB):
//   wgt   f32  @0           4,718,592   adaptive weights (F1->ada1, F2->ada2)
//   xh    bf16 @4,718,592  16,777,216   x NHWC
//   mh    bf16 @21,495,808 16,777,216   mask NHWC; x2h reuses after F1
//   wb    bf16 @38,273,024    770,048   prepped conv weights
//   resh  bf16 @39,043,072 16,777,216   residual, bf16 NHWC (conv1 -> ada2)
// d_out scratch: out_x lower = maska_h, out_x upper = xa_h, out_m = x1_h.
// Launches: prep -> F1 -> c3_1 -> ada1 -> F2 -> c3_2 -> conv1 -> ada2.
// ---------------------------------------------------------------------------
extern "C" void kernel_launch(void* const* d_in, const int* in_sizes, int n_in,
                              void* d_out, int out_size, void* d_ws, size_t ws_size,
                              hipStream_t stream)
{
    const float* x     = (const float*)d_in[0];
    const float* mask  = (const float*)d_in[1];
    const float* aw1_w = (const float*)d_in[2];
    const float* aw1_b = (const float*)d_in[3];
    const float* mt1_w = (const float*)d_in[4];
    const float* mt1_b = (const float*)d_in[5];
    const float* c1_w  = (const float*)d_in[6];
    const float* c1_b  = (const float*)d_in[7];
    const float* aw2_w = (const float*)d_in[8];
    const float* aw2_b = (const float*)d_in[9];
    const float* mt2_w = (const float*)d_in[10];
    const float* mt2_b = (const float*)d_in[11];
    const float* c2_w  = (const float*)d_in[12];
    const float* c2_b  = (const float*)d_in[13];
    const float* cr_w  = (const float*)d_in[14];
    const float* cr_b  = (const float*)d_in[15];

    float* out_x = (float*)d_out;
    float* out_m = (float*)d_out + 8388608;

    float*  wgt   = (float*)d_ws;
    __bf16* xh    = (__bf16*)((char*)d_ws + 4718592);
    __bf16* mh    = (__bf16*)((char*)d_ws + 21495808);
    __bf16* x2h   = mh;                                // sequential live ranges
    __bf16* wbase = (__bf16*)((char*)d_ws + 38273024);
    __bf16* wb_c1 = wbase;             // 36864 elems
    __bf16* wb_c2 = wbase + 36864;     // 36864
    __bf16* wb_F1 = wbase + 73728;     // 153600
    __bf16* wb_F2 = wbase + 227328;    // 153600
    __bf16* wb_cr = wbase + 380928;    // 4096
    __bf16* resh  = (__bf16*)((char*)d_ws + 39043072);

    __bf16* maska_h = (__bf16*)out_x;               // lower 16.78 MB
    __bf16* xa_h    = (__bf16*)out_x + 8388608;     // upper 16.78 MB
    __bf16* x1_h    = (__bf16*)out_m;               // lower 16.78 MB

    dim3 blk(256);
    dim3 gconv(16, 16, 2);
    dim3 gada(4096);

    // 0. merged prep
    k_prep<<<dim3(2528), blk, 0, stream>>>(x, mask, c1_w, c2_w,
        mt1_w, aw1_w, mt2_w, aw2_w, cr_w,
        xh, mh, wb_c1, wb_c2, wb_F1, wb_F2, wb_cr);

    // 1. F1(mh): maska = lrelu(mt1) -> maska_h (bf16), weight1 = aw1 -> wgt
    k_conv5<0><<<gconv, blk, 0, stream>>>(mh, wb_F1, mt1_b, aw1_b,
                                          nullptr, maska_h, wgt);
    // 2. x1 = conv3x3(xh, c1) -> x1_h
    k_conv3<<<gconv, blk, 0, stream>>>(xh, wb_c1, c1_b, x1_h);
    // 3. xa = lrelu(ada(wgt, x1)) -> xa_h
    k_ada1<<<gada, blk, 0, stream>>>(wgt, x1_h, xa_h);
    // 4. F2(maska_h): final mask = lrelu(mt2) -> out_m (f32), weight2 -> wgt
    k_conv5<1><<<gconv, blk, 0, stream>>>(maska_h, wb_F2, mt2_b, aw2_b,
                                          out_m, nullptr, wgt);
    // 5. x2 = conv3x3(xa_h, c2) -> x2h
    k_conv3<<<gconv, blk, 0, stream>>>(xa_h, wb_c2, c2_b, x2h);
    // 6. res = conv1x1(xh) via MFMA -> resh (bf16 NHWC)
    k_conv1<<<gconv, blk, 0, stream>>>(xh, wb_cr, cr_b, resh);
    // 7. out_x = lrelu(ada(wgt, x2)) + res   (pure write)
    k_ada2<<<gada, blk, 0, stream>>>(wgt, x2h, resh, out_x);
}